// Round 2
// baseline (375.669 us; speedup 1.0000x reference)
//
#include <hip/hip_runtime.h>

#define Bb 8
#define Nn 64
#define Hh 152
#define Ww 272
#define HW (Hh * Ww)
#define EMB 128
#define NC 500
#define EPSV 1e-4f

// ---------------------------------------------------------------------------
// Kernel 1: heatmap focal loss over B*H*W pixels.
// gt_hm reconstructed per-pixel from the 64 centers (LDS) with the 5-tap
// gaussian table. pos test (gt_hm==1.0f) is robust: center tap is exactly 1.0,
// min product of two taps is 0.641 so multi-touch pixels are >= 1.28.
// ---------------------------------------------------------------------------
__global__ void hm_loss_kernel(const float* __restrict__ hm,
                               const float* __restrict__ gt,
                               float* __restrict__ acc) {
    __shared__ int s_r[Nn];
    __shared__ int s_c[Nn];
    const int b = blockIdx.x;
    const int t = threadIdx.x;

    if (t < Nn) {
        const float* g5 = gt + ((size_t)b * Nn + t) * 5;
        float xc = g5[1], yc = g5[2];
        float rf = yc * (float)Hh;
        float cf = xc * (float)Ww;
        int rr = (int)floorf(rf); rr = min(max(rr, 0), Hh - 1);
        int cc = (int)floorf(cf); cc = min(max(cc, 0), Ww - 1);
        s_r[t] = rr;
        s_c[t] = cc;
    }
    __syncthreads();

    // gaussian taps: exp(-((i-2)/3)^2 / 2); tap[2] == 1.0f exactly
    float g[5];
#pragma unroll
    for (int i = 0; i < 5; ++i) {
        float tv = (float)(i - 2) / 3.0f;
        g[i] = expf(-0.5f * tv * tv);
    }

    float pos_l = 0.0f, neg_l = 0.0f, np = 0.0f;
    const float* hmb = hm + (size_t)b * HW;

    for (int p = blockIdx.y * blockDim.x + t; p < HW; p += gridDim.y * blockDim.x) {
        int y = p / Ww;
        int x = p - y * Ww;
        float h = hmb[p];
        float pred = 1.0f / (1.0f + expf(-h));
        pred = fminf(fmaxf(pred, EPSV), 1.0f - EPSV);

        float gh = 0.0f;
#pragma unroll 8
        for (int n = 0; n < Nn; ++n) {
            int dy = y - s_r[n];
            int dx = x - s_c[n];
            if (dy >= -2 && dy <= 2 && dx >= -2 && dx <= 2)
                gh += g[dy + 2] * g[dx + 2];
        }

        if (gh == 1.0f) {
            float om = 1.0f - pred;
            pos_l += om * om * logf(pred);
            np += 1.0f;
        } else if (gh < 1.0f) {
            float om = 1.0f - gh;
            float w = om * om;
            w = w * w;
            neg_l += w * pred * pred * logf(1.0f - pred);
        }
    }

    // wave(64) reduce, then one atomic per wave
#pragma unroll
    for (int off = 32; off > 0; off >>= 1) {
        pos_l += __shfl_down(pos_l, off);
        neg_l += __shfl_down(neg_l, off);
        np    += __shfl_down(np, off);
    }
    if ((t & 63) == 0) {
        atomicAdd(&acc[2], pos_l);
        atomicAdd(&acc[3], neg_l);
        atomicAdd(&acc[4], np);
    }
}

// ---------------------------------------------------------------------------
// Kernel 2: per-sample (B*N=512 blocks): ReID CE + box/offset L1 terms.
// Wave-per-class mapping: 64 lanes read one 128-float W_cls row as float2
// (coalesced 512B segment), 2 FMAs vs LDS feat, shuffle-xor reduce.
// This replaces the thread-per-class version whose 64-lines-per-instruction
// gather generated ~16x L2 transaction amplification.
// ---------------------------------------------------------------------------
__global__ void sample_kernel(const float* __restrict__ bs,
                              const float* __restrict__ off,
                              const float* __restrict__ reid,
                              const float* __restrict__ gt,
                              const float* __restrict__ Wc,
                              const float* __restrict__ bc,
                              float* __restrict__ acc) {
    const int s = blockIdx.x;          // 0..B*N-1
    const int b = s / Nn;
    const int t = threadIdx.x;
    const int wave = t >> 6;           // 0..3
    const int lane = t & 63;

    __shared__ float s_feat[EMB];
    __shared__ float s_log[NC];
    __shared__ float s_red[256];

    const float* g5 = gt + (size_t)s * 5;
    const float tf = g5[0];
    const float xc = g5[1], yc = g5[2];
    const float bw = g5[3], bh = g5[4];

    const float rf = yc * (float)Hh;
    const float cf = xc * (float)Ww;
    const float fr = floorf(rf);
    const float fc = floorf(cf);
    const int rr = min(max((int)fr, 0), Hh - 1);
    const int cc = min(max((int)fc, 0), Ww - 1);
    const size_t pix = (size_t)rr * Ww + cc;

    if (t < EMB)
        s_feat[t] = reid[(size_t)b * EMB * HW + (size_t)t * HW + pix];
    __syncthreads();

    const float fa = s_feat[2 * lane];
    const float fb = s_feat[2 * lane + 1];

    // wave-per-class: coalesced float2 row read + butterfly reduce
    float lmax = -INFINITY;
    for (int c = wave; c < NC; c += 4) {
        const float2 w2 = ((const float2*)(Wc + (size_t)c * EMB))[lane];
        float p = fmaf(w2.x, fa, w2.y * fb);
#pragma unroll
        for (int o = 32; o > 0; o >>= 1)
            p += __shfl_xor(p, o);
        p += bc[c];                    // all lanes hold the full logit now
        if (lane == 0) s_log[c] = p;
        lmax = fmaxf(lmax, p);
    }

    s_red[t] = lmax;
    __syncthreads();
#pragma unroll
    for (int w = 128; w > 0; w >>= 1) {
        if (t < w) s_red[t] = fmaxf(s_red[t], s_red[t + w]);
        __syncthreads();
    }
    const float mv = s_red[0];
    __syncthreads();

    float lsum = 0.0f;
    for (int c = t; c < NC; c += 256)
        lsum += expf(s_log[c] - mv);
    s_red[t] = lsum;
    __syncthreads();
#pragma unroll
    for (int w = 128; w > 0; w >>= 1) {
        if (t < w) s_red[t] += s_red[t + w];
        __syncthreads();
    }

    if (t == 0) {
        int lab = (tf > (float)NC) ? (NC - 1) : ((int)tf - 1);
        lab = min(max(lab, 0), NC - 1);
        float ce = logf(s_red[0]) + mv - s_log[lab];
        atomicAdd(&acc[5], ce);

        // box-size + offset L1 at this center
        const float* bsb = bs  + (size_t)b * 2 * HW;
        const float* ofb = off + (size_t)b * 2 * HW;
        float bl = fabsf(bsb[pix]      - bh * 608.0f)
                 + fabsf(bsb[HW + pix] - bw * 1088.0f);
        float ol = fabsf(ofb[pix]      - (rf - fr))
                 + fabsf(ofb[HW + pix] - (cf - fc));
        atomicAdd(&acc[0], bl);
        atomicAdd(&acc[1], ol);
    }
}

// ---------------------------------------------------------------------------
// Kernel 3: finalize the 6 scalars.
// out = (bs_loss, off_loss, det_loss, hm_loss, reid_loss, total)
// ---------------------------------------------------------------------------
__global__ void finalize_kernel(const float* __restrict__ acc,
                                float* __restrict__ out) {
    const float bsl = acc[0];
    const float ofl = acc[1];
    const float pl  = acc[2];
    const float nl  = acc[3];
    const float np  = acc[4];
    const float re  = acc[5];
    const float hm  = (np >= 1.0f) ? (-(pl + nl) / np) : (-nl);
    const float reid = re / (float)Nn;
    const float det  = hm + 0.1f * bsl + ofl;
    out[0] = bsl;
    out[1] = ofl;
    out[2] = det;
    out[3] = hm;
    out[4] = reid;
    out[5] = det + reid;
}

extern "C" void kernel_launch(void* const* d_in, const int* in_sizes, int n_in,
                              void* d_out, int out_size, void* d_ws, size_t ws_size,
                              hipStream_t stream) {
    const float* hm   = (const float*)d_in[0];  // (B,1,H,W)
    const float* bs   = (const float*)d_in[1];  // (B,2,H,W)
    const float* off  = (const float*)d_in[2];  // (B,2,H,W)
    const float* reid = (const float*)d_in[3];  // (B,128,H,W)
    const float* gt   = (const float*)d_in[4];  // (B,N,5)
    const float* Wc   = (const float*)d_in[5];  // (500,128)
    const float* bc   = (const float*)d_in[6];  // (500,)
    float* out = (float*)d_out;
    float* acc = (float*)d_ws;                  // 6 accumulators

    hipMemsetAsync(acc, 0, 8 * sizeof(float), stream);

    hipLaunchKernelGGL(hm_loss_kernel, dim3(Bb, 32), dim3(256), 0, stream,
                       hm, gt, acc);
    hipLaunchKernelGGL(sample_kernel, dim3(Bb * Nn), dim3(256), 0, stream,
                       bs, off, reid, gt, Wc, bc, acc);
    hipLaunchKernelGGL(finalize_kernel, dim3(1), dim3(1), 0, stream,
                       acc, out);
}

// Round 3
// 306.867 us; speedup vs baseline: 1.2242x; 1.2242x over previous
//
#include <hip/hip_runtime.h>

#define Bb 8
#define Nn 64
#define Hh 152
#define Ww 272
#define HW (Hh * Ww)
#define EMB 128
#define NC 500
#define EPSV 1e-4f

#define HM_BLOCKS 256          // 8 batches x 32 tiles
#define SAMP_BLOCKS (Bb * Nn)  // 512
#define TOTAL_BLOCKS (HM_BLOCKS + SAMP_BLOCKS)

// ---------------------------------------------------------------------------
// One fused kernel. blocks [0,256): heatmap focal loss; [256,768): per-sample
// ReID CE + L1 terms. Last block to finish (device-scope counter) finalizes
// the 6 output scalars. acc layout: [0]=bs [1]=off [2]=pos [3]=neg [4]=npos
// [5]=reid_ce [6]=(int)completion counter.  Zeroed by hipMemsetAsync.
// ---------------------------------------------------------------------------
__global__ void fused_kernel(const float* __restrict__ hm,
                             const float* __restrict__ bs,
                             const float* __restrict__ off,
                             const float* __restrict__ reid,
                             const float* __restrict__ gt,
                             const float* __restrict__ Wc,
                             const float* __restrict__ bc,
                             float* __restrict__ acc,
                             float* __restrict__ out) {
    __shared__ union {
        struct { int r[Nn]; int c[Nn]; } hm며;
        struct { float feat[EMB]; float logit[NC]; float red[256]; } sp;
    } u;
    const int gb = blockIdx.x;
    const int t = threadIdx.x;

    if (gb < HM_BLOCKS) {
        // ----------------- heatmap focal loss -----------------
        const int b = gb >> 5;         // 8 batches
        const int tile = gb & 31;      // 32 tiles per batch

        if (t < Nn) {
            const float* g5 = gt + ((size_t)b * Nn + t) * 5;
            float rf = g5[2] * (float)Hh;
            float cf = g5[1] * (float)Ww;
            int rr = (int)floorf(rf); rr = min(max(rr, 0), Hh - 1);
            int cc = (int)floorf(cf); cc = min(max(cc, 0), Ww - 1);
            u.hm며.r[t] = rr;
            u.hm며.c[t] = cc;
        }
        __syncthreads();

        // gaussian taps: exp(-((i-2)/3)^2/2); tap[2]==1.0f exactly.
        // pos test (gh==1.0f) robust: min 2-tap product 0.641 -> multi-touch
        // pixels >= 1.28; single-touch non-center < 1.0.
        float g[5];
#pragma unroll
        for (int i = 0; i < 5; ++i) {
            float tv = (float)(i - 2) / 3.0f;
            g[i] = expf(-0.5f * tv * tv);
        }

        float pos_l = 0.0f, neg_l = 0.0f, np = 0.0f;
        const float* hmb = hm + (size_t)b * HW;

        for (int p = tile * 256 + t; p < HW; p += 32 * 256) {
            int y = p / Ww;
            int x = p - y * Ww;
            float h = hmb[p];
            float pred = 1.0f / (1.0f + expf(-h));
            pred = fminf(fmaxf(pred, EPSV), 1.0f - EPSV);

            float gh = 0.0f;
#pragma unroll 8
            for (int n = 0; n < Nn; ++n) {
                int dy = y - u.hm며.r[n];
                int dx = x - u.hm며.c[n];
                if (dy >= -2 && dy <= 2 && dx >= -2 && dx <= 2)
                    gh += g[dy + 2] * g[dx + 2];
            }

            if (gh == 1.0f) {
                float om = 1.0f - pred;
                pos_l += om * om * logf(pred);
                np += 1.0f;
            } else if (gh < 1.0f) {
                float om = 1.0f - gh;
                float w = om * om;
                w = w * w;
                neg_l += w * pred * pred * logf(1.0f - pred);
            }
        }

#pragma unroll
        for (int o = 32; o > 0; o >>= 1) {
            pos_l += __shfl_down(pos_l, o);
            neg_l += __shfl_down(neg_l, o);
            np    += __shfl_down(np, o);
        }
        if ((t & 63) == 0) {
            atomicAdd(&acc[2], pos_l);
            atomicAdd(&acc[3], neg_l);
            atomicAdd(&acc[4], np);
        }
        __syncthreads();
    } else {
        // ----------------- per-sample: ReID CE + L1 -----------------
        const int s = gb - HM_BLOCKS;  // 0..511
        const int b = s / Nn;
        const int wave = t >> 6;
        const int lane = t & 63;

        const float* g5 = gt + (size_t)s * 5;
        const float tf = g5[0];
        const float xc = g5[1], yc = g5[2];
        const float bw = g5[3], bh = g5[4];

        const float rf = yc * (float)Hh;
        const float cf = xc * (float)Ww;
        const float fr = floorf(rf);
        const float fc = floorf(cf);
        const int rr = min(max((int)fr, 0), Hh - 1);
        const int cc = min(max((int)fc, 0), Ww - 1);
        const size_t pix = (size_t)rr * Ww + cc;

        if (t < EMB)
            u.sp.feat[t] = reid[(size_t)b * EMB * HW + (size_t)t * HW + pix];
        __syncthreads();

        const float fa = u.sp.feat[2 * lane];
        const float fb = u.sp.feat[2 * lane + 1];

        // wave-per-class, 8 classes in flight: 8 independent shuffle chains
        // overlap in the LDS pipe (fixes the R2 latency serialization).
        float lmax = -INFINITY;
        for (int c0 = wave * 8; c0 < NC; c0 += 32) {
            float p[8];
#pragma unroll
            for (int gi = 0; gi < 8; ++gi) {
                int c = c0 + gi;
                float2 w2 = make_float2(0.0f, 0.0f);
                if (c < NC) w2 = ((const float2*)(Wc + (size_t)c * EMB))[lane];
                p[gi] = fmaf(w2.x, fa, w2.y * fb);
            }
#pragma unroll
            for (int o = 32; o > 0; o >>= 1) {
#pragma unroll
                for (int gi = 0; gi < 8; ++gi)
                    p[gi] += __shfl_xor(p[gi], o);
            }
#pragma unroll
            for (int gi = 0; gi < 8; ++gi) {
                int c = c0 + gi;
                if (c < NC) {
                    float v = p[gi] + bc[c];
                    if (lane == 0) u.sp.logit[c] = v;
                    lmax = fmaxf(lmax, v);
                }
            }
        }

        u.sp.red[t] = lmax;
        __syncthreads();
#pragma unroll
        for (int w = 128; w > 0; w >>= 1) {
            if (t < w) u.sp.red[t] = fmaxf(u.sp.red[t], u.sp.red[t + w]);
            __syncthreads();
        }
        const float mv = u.sp.red[0];
        __syncthreads();

        float lsum = 0.0f;
        for (int c = t; c < NC; c += 256)
            lsum += expf(u.sp.logit[c] - mv);
        u.sp.red[t] = lsum;
        __syncthreads();
#pragma unroll
        for (int w = 128; w > 0; w >>= 1) {
            if (t < w) u.sp.red[t] += u.sp.red[t + w];
            __syncthreads();
        }

        if (t == 0) {
            int lab = (tf > (float)NC) ? (NC - 1) : ((int)tf - 1);
            lab = min(max(lab, 0), NC - 1);
            float ce = logf(u.sp.red[0]) + mv - u.sp.logit[lab];
            atomicAdd(&acc[5], ce);

            const float* bsb = bs  + (size_t)b * 2 * HW;
            const float* ofb = off + (size_t)b * 2 * HW;
            float bl = fabsf(bsb[pix]      - bh * 608.0f)
                     + fabsf(bsb[HW + pix] - bw * 1088.0f);
            float ol = fabsf(ofb[pix]      - (rf - fr))
                     + fabsf(ofb[HW + pix] - (cf - fc));
            atomicAdd(&acc[0], bl);
            atomicAdd(&acc[1], ol);
        }
        __syncthreads();
    }

    // ----------------- last-block finalize -----------------
    if (t == 0) {
        __threadfence();
        int done = atomicAdd((int*)(acc + 6), 1);
        if (done == TOTAL_BLOCKS - 1) {
            // atomic-RMW reads: guaranteed coherent view of the accumulators
            float bsl = atomicAdd(&acc[0], 0.0f);
            float ofl = atomicAdd(&acc[1], 0.0f);
            float pl  = atomicAdd(&acc[2], 0.0f);
            float nl  = atomicAdd(&acc[3], 0.0f);
            float np  = atomicAdd(&acc[4], 0.0f);
            float re  = atomicAdd(&acc[5], 0.0f);
            float hmv  = (np >= 1.0f) ? (-(pl + nl) / np) : (-nl);
            float reidl = re / (float)Nn;
            float det  = hmv + 0.1f * bsl + ofl;
            out[0] = bsl;
            out[1] = ofl;
            out[2] = det;
            out[3] = hmv;
            out[4] = reidl;
            out[5] = det + reidl;
        }
    }
}

extern "C" void kernel_launch(void* const* d_in, const int* in_sizes, int n_in,
                              void* d_out, int out_size, void* d_ws, size_t ws_size,
                              hipStream_t stream) {
    const float* hm   = (const float*)d_in[0];  // (B,1,H,W)
    const float* bs   = (const float*)d_in[1];  // (B,2,H,W)
    const float* off  = (const float*)d_in[2];  // (B,2,H,W)
    const float* reid = (const float*)d_in[3];  // (B,128,H,W)
    const float* gt   = (const float*)d_in[4];  // (B,N,5)
    const float* Wc   = (const float*)d_in[5];  // (500,128)
    const float* bc   = (const float*)d_in[6];  // (500,)
    float* out = (float*)d_out;
    float* acc = (float*)d_ws;                  // 6 accumulators + counter

    hipMemsetAsync(acc, 0, 8 * sizeof(float), stream);
    hipLaunchKernelGGL(fused_kernel, dim3(TOTAL_BLOCKS), dim3(256), 0, stream,
                       hm, bs, off, reid, gt, Wc, bc, acc, out);
}

// Round 4
// 283.260 us; speedup vs baseline: 1.3262x; 1.0833x over previous
//
#include <hip/hip_runtime.h>

#define Bb 8
#define Nn 64
#define Hh 152
#define Ww 272
#define HW (Hh * Ww)
#define EMB 128
#define NC 500
#define EPSV 1e-4f

#define HM_BLOCKS 256            // 8 batches x 32 tiles
#define SAMP_BLOCKS 64           // 64 blocks x 8 samples
#define TOTAL_BLOCKS (HM_BLOCKS + SAMP_BLOCKS)
// partials: float[TOTAL_BLOCKS][8] in d_ws. slots: 0=bs 1=off 2=pos 3=neg
// 4=npos 5=ce. Every block overwrites its full row -> no zeroing needed.

// ---------------------------------------------------------------------------
// Main kernel: NO atomics, NO fences. Each block plain-stores its partial
// sums to a private 32B row. (R3 post-mortem: ~5K same-line atomic RMWs were
// the prime suspect for the constant 103us; this kernel has zero.)
// ---------------------------------------------------------------------------
__global__ void main_kernel(const float* __restrict__ hm,
                            const float* __restrict__ bs,
                            const float* __restrict__ off,
                            const float* __restrict__ reid,
                            const float* __restrict__ gt,
                            const float* __restrict__ Wc,
                            const float* __restrict__ bc,
                            float* __restrict__ partials) {
    __shared__ int   s_r[Nn];
    __shared__ int   s_c[Nn];
    __shared__ float s_feat[EMB];
    __shared__ float s_log[NC];
    __shared__ float s_max4[4];
    __shared__ float s_sum4[4];

    const int gb = blockIdx.x;
    const int t = threadIdx.x;
    const int wave = t >> 6;
    const int lane = t & 63;

    float out0 = 0.0f, out1 = 0.0f, out2 = 0.0f,
          out3 = 0.0f, out4 = 0.0f, out5 = 0.0f;

    if (gb < HM_BLOCKS) {
        // ----------------- heatmap focal loss -----------------
        const int b = gb >> 5;
        const int tile = gb & 31;

        if (t < Nn) {
            const float* g5 = gt + ((size_t)b * Nn + t) * 5;
            float rf = g5[2] * (float)Hh;
            float cf = g5[1] * (float)Ww;
            int rr = (int)floorf(rf); rr = min(max(rr, 0), Hh - 1);
            int cc = (int)floorf(cf); cc = min(max(cc, 0), Ww - 1);
            s_r[t] = rr;
            s_c[t] = cc;
        }
        __syncthreads();

        // taps: exp(-((i-2)/3)^2/2); tap[2]==1.0 exactly. pos test gh==1.0
        // robust: min 2-tap product 0.641 -> multi-touch >= 1.28.
        float g[5];
#pragma unroll
        for (int i = 0; i < 5; ++i) {
            float tv = (float)(i - 2) / 3.0f;
            g[i] = expf(-0.5f * tv * tv);
        }

        float pos_l = 0.0f, neg_l = 0.0f, np = 0.0f;
        const float* hmb = hm + (size_t)b * HW;

        for (int p = tile * 256 + t; p < HW; p += 32 * 256) {
            int y = p / Ww;
            int x = p - y * Ww;
            float h = hmb[p];
            float pred = 1.0f / (1.0f + expf(-h));
            pred = fminf(fmaxf(pred, EPSV), 1.0f - EPSV);

            float gh = 0.0f;
#pragma unroll 8
            for (int n = 0; n < Nn; ++n) {
                int dy = y - s_r[n];
                int dx = x - s_c[n];
                if (dy >= -2 && dy <= 2 && dx >= -2 && dx <= 2)
                    gh += g[dy + 2] * g[dx + 2];
            }

            if (gh == 1.0f) {
                float om = 1.0f - pred;
                pos_l += om * om * logf(pred);
                np += 1.0f;
            } else if (gh < 1.0f) {
                float om = 1.0f - gh;
                float w = om * om;
                w = w * w;
                neg_l += w * pred * pred * logf(1.0f - pred);
            }
        }

        // wave reduce then cross-wave via LDS
#pragma unroll
        for (int o = 32; o > 0; o >>= 1) {
            pos_l += __shfl_down(pos_l, o);
            neg_l += __shfl_down(neg_l, o);
            np    += __shfl_down(np, o);
        }
        if (lane == 0) {
            s_log[wave]      = pos_l;
            s_log[wave + 4]  = neg_l;
            s_log[wave + 8]  = np;
        }
        __syncthreads();
        if (t == 0) {
            out2 = s_log[0] + s_log[1] + s_log[2] + s_log[3];
            out3 = s_log[4] + s_log[5] + s_log[6] + s_log[7];
            out4 = s_log[8] + s_log[9] + s_log[10] + s_log[11];
        }
    } else {
        // ----------------- 8 samples per block: ReID CE + L1 -----------------
        const int sblk = gb - HM_BLOCKS;   // 0..63
        const int b = sblk >> 3;
        const int n0 = (sblk & 7) * 8;

        float ce_sum = 0.0f, bl_sum = 0.0f, ol_sum = 0.0f;

        for (int i = 0; i < 8; ++i) {
            const int s = b * Nn + n0 + i;
            const float* g5 = gt + (size_t)s * 5;
            const float tf = g5[0];
            const float xc = g5[1], yc = g5[2];
            const float bw = g5[3], bh = g5[4];

            const float rf = yc * (float)Hh;
            const float cf = xc * (float)Ww;
            const float fr = floorf(rf);
            const float fc = floorf(cf);
            const int rr = min(max((int)fr, 0), Hh - 1);
            const int cc = min(max((int)fc, 0), Ww - 1);
            const size_t pix = (size_t)rr * Ww + cc;

            __syncthreads();   // protect s_feat/s_log from previous iteration
            if (t < EMB)
                s_feat[t] = reid[(size_t)b * EMB * HW + (size_t)t * HW + pix];
            __syncthreads();

            // thread-per-class, 2 classes/thread, float4 row reads
            float lmax = -INFINITY;
            const float4* f4 = (const float4*)s_feat;
#pragma unroll
            for (int half = 0; half < 2; ++half) {
                const int c = t + half * 256;
                if (c < NC) {
                    const float4* wr = (const float4*)(Wc + (size_t)c * EMB);
                    float d = bc[c];
#pragma unroll 8
                    for (int k = 0; k < EMB / 4; ++k) {
                        float4 w4 = wr[k];
                        float4 fv = f4[k];
                        d += w4.x * fv.x + w4.y * fv.y
                           + w4.z * fv.z + w4.w * fv.w;
                    }
                    s_log[c] = d;
                    lmax = fmaxf(lmax, d);
                }
            }

            // block max: wave shuffle + 4-slot LDS
#pragma unroll
            for (int o = 32; o > 0; o >>= 1)
                lmax = fmaxf(lmax, __shfl_xor(lmax, o));
            if (lane == 0) s_max4[wave] = lmax;
            __syncthreads();
            const float mv = fmaxf(fmaxf(s_max4[0], s_max4[1]),
                                   fmaxf(s_max4[2], s_max4[3]));

            float lsum = 0.0f;
#pragma unroll
            for (int half = 0; half < 2; ++half) {
                const int c = t + half * 256;
                if (c < NC) lsum += expf(s_log[c] - mv);
            }
#pragma unroll
            for (int o = 32; o > 0; o >>= 1)
                lsum += __shfl_xor(lsum, o);
            if (lane == 0) s_sum4[wave] = lsum;
            __syncthreads();

            if (t == 0) {
                const float tot = s_sum4[0] + s_sum4[1] + s_sum4[2] + s_sum4[3];
                int lab = (tf > (float)NC) ? (NC - 1) : ((int)tf - 1);
                lab = min(max(lab, 0), NC - 1);
                ce_sum += logf(tot) + mv - s_log[lab];

                const float* bsb = bs  + (size_t)b * 2 * HW;
                const float* ofb = off + (size_t)b * 2 * HW;
                bl_sum += fabsf(bsb[pix]      - bh * 608.0f)
                        + fabsf(bsb[HW + pix] - bw * 1088.0f);
                ol_sum += fabsf(ofb[pix]      - (rf - fr))
                        + fabsf(ofb[HW + pix] - (cf - fc));
            }
        }
        if (t == 0) {
            out0 = bl_sum;
            out1 = ol_sum;
            out5 = ce_sum;
        }
    }

    // plain store of this block's full row (8 floats, block-private line)
    if (t == 0) {
        float* row = partials + (size_t)gb * 8;
        row[0] = out0; row[1] = out1; row[2] = out2; row[3] = out3;
        row[4] = out4; row[5] = out5; row[6] = 0.0f; row[7] = 0.0f;
    }
}

// ---------------------------------------------------------------------------
// Final reduce: 1 block, stream-ordered after main_kernel (dispatch boundary
// provides cross-XCD visibility). Sums 320 rows, writes the 6 outputs.
// ---------------------------------------------------------------------------
__global__ void final_kernel(const float* __restrict__ partials,
                             float* __restrict__ out) {
    __shared__ float s_fin[4][6];
    const int t = threadIdx.x;
    const int wave = t >> 6;
    const int lane = t & 63;

    float v[6] = {0, 0, 0, 0, 0, 0};
    for (int r = t; r < TOTAL_BLOCKS; r += 256) {
        const float* row = partials + (size_t)r * 8;
#pragma unroll
        for (int j = 0; j < 6; ++j) v[j] += row[j];
    }
#pragma unroll
    for (int o = 32; o > 0; o >>= 1)
#pragma unroll
        for (int j = 0; j < 6; ++j) v[j] += __shfl_xor(v[j], o);
    if (lane == 0)
#pragma unroll
        for (int j = 0; j < 6; ++j) s_fin[wave][j] = v[j];
    __syncthreads();

    if (t == 0) {
        float a[6];
#pragma unroll
        for (int j = 0; j < 6; ++j)
            a[j] = s_fin[0][j] + s_fin[1][j] + s_fin[2][j] + s_fin[3][j];
        const float bsl = a[0], ofl = a[1], pl = a[2],
                    nl = a[3], np = a[4], re = a[5];
        const float hmv   = (np >= 1.0f) ? (-(pl + nl) / np) : (-nl);
        const float reidl = re / (float)Nn;
        const float det   = hmv + 0.1f * bsl + ofl;
        out[0] = bsl;
        out[1] = ofl;
        out[2] = det;
        out[3] = hmv;
        out[4] = reidl;
        out[5] = det + reidl;
    }
}

extern "C" void kernel_launch(void* const* d_in, const int* in_sizes, int n_in,
                              void* d_out, int out_size, void* d_ws, size_t ws_size,
                              hipStream_t stream) {
    const float* hm   = (const float*)d_in[0];  // (B,1,H,W)
    const float* bs   = (const float*)d_in[1];  // (B,2,H,W)
    const float* off  = (const float*)d_in[2];  // (B,2,H,W)
    const float* reid = (const float*)d_in[3];  // (B,128,H,W)
    const float* gt   = (const float*)d_in[4];  // (B,N,5)
    const float* Wc   = (const float*)d_in[5];  // (500,128)
    const float* bc   = (const float*)d_in[6];  // (500,)
    float* out = (float*)d_out;
    float* partials = (float*)d_ws;             // [320][8] floats

    hipLaunchKernelGGL(main_kernel, dim3(TOTAL_BLOCKS), dim3(256), 0, stream,
                       hm, bs, off, reid, gt, Wc, bc, partials);
    hipLaunchKernelGGL(final_kernel, dim3(1), dim3(256), 0, stream,
                       partials, out);
}